// Round 3
// baseline (1967.322 us; speedup 1.0000x reference)
//
#include <hip/hip_runtime.h>
#include <hip/hip_bf16.h>

#define BATCH 4
#define C 512
#define H 128
#define W 128
#define HW (H*W)            // 16384
#define CHW (C*HW)          // 8388608
#define NH 8
#define D 64
#define P 128
#define BB (BATCH*W)        // 512
#define OUT0_SIZE ((size_t)BATCH*C*H*W)   // 33554432

// ---------------------------------------------------------------------------
// K1: value[b][o][h][w] = bv[o] + sum_c Wv[o][c] * X[b][c][h][w]
// grid.x = BATCH*H (one (b,h) row, 128 w), grid.y = C/128
// ---------------------------------------------------------------------------
__global__ __launch_bounds__(256) void k_gemm_value(
    const float* __restrict__ X, const float* __restrict__ Wv,
    const float* __restrict__ bv, float* __restrict__ out)
{
    const int row = blockIdx.x;
    const int b = row >> 7, h = row & 127;
    const int o0 = blockIdx.y * 128;
    const float* xbase = X + (size_t)b*CHW + (size_t)h*W;
    __shared__ float sA[16][132];   // [cc][m] = Wv[o0+m][c0+cc]
    __shared__ float sB[16][132];   // [cc][w]
    const int tid = threadIdx.x;
    const int tx = tid & 15, ty = tid >> 4;
    float acc[8][8] = {};
    for (int c0 = 0; c0 < C; c0 += 16) {
        #pragma unroll
        for (int it = 0; it < 8; it++) {
            int f = tid + it*256;
            int m = f >> 4, cc = f & 15;
            sA[cc][m] = Wv[(size_t)(o0+m)*C + c0 + cc];
        }
        #pragma unroll
        for (int it = 0; it < 8; it++) {
            int f = tid + it*256;
            int cc = f >> 7, w = f & 127;
            sB[cc][w] = xbase[(size_t)(c0+cc)*HW + w];
        }
        __syncthreads();
        #pragma unroll
        for (int cc = 0; cc < 16; cc++) {
            float a[8], br[8];
            #pragma unroll
            for (int m = 0; m < 8; m++) a[m] = sA[cc][ty*8+m];
            #pragma unroll
            for (int n = 0; n < 8; n++) br[n] = sB[cc][tx*8+n];
            #pragma unroll
            for (int m = 0; m < 8; m++)
                #pragma unroll
                for (int n = 0; n < 8; n++) acc[m][n] += a[m]*br[n];
        }
        __syncthreads();
    }
    #pragma unroll
    for (int m = 0; m < 8; m++) {
        int o = o0 + ty*8 + m;
        float bias = bv[o];
        float* dst = out + (size_t)b*CHW + (size_t)o*HW + (size_t)h*W + tx*8;
        #pragma unroll
        for (int n = 0; n < 8; n++) dst[n] = acc[m][n] + bias;
    }
}

// ---------------------------------------------------------------------------
// K2: v[bw][n][i][dd] = value[b][n*64+dd][i][w]   (transpose dd <-> w)
// grid = BATCH*NH*P blocks
// ---------------------------------------------------------------------------
__global__ __launch_bounds__(256) void k_transpose_v(
    const float* __restrict__ val, float* __restrict__ v)
{
    int g = blockIdx.x;
    int i = g & 127, n = (g >> 7) & 7, b = g >> 10;
    __shared__ float s[64][129];
    int tid = threadIdx.x;
    const float* src = val + (size_t)b*CHW + (size_t)(n*64)*HW + (size_t)i*W;
    #pragma unroll
    for (int it = 0; it < 32; it++) {
        int f = tid + it*256;
        int dd = f >> 7, w = f & 127;
        s[dd][w] = src[(size_t)dd*HW + w];
    }
    __syncthreads();
    float* dst = v + (size_t)n*8192 + (size_t)i*64;
    #pragma unroll
    for (int it = 0; it < 32; it++) {
        int f = tid + it*256;
        int w = f >> 6, dd = f & 63;
        dst[(size_t)(b*W + w)*65536 + dd] = s[dd][w];
    }
}

// ---------------------------------------------------------------------------
// K3: vm[g] = mean(v[g*8192 .. +8192)),  g = bw*8+n  (4096 blocks)
// ---------------------------------------------------------------------------
__global__ __launch_bounds__(256) void k_vm(
    const float* __restrict__ v, float* __restrict__ vm)
{
    int g = blockIdx.x;
    const float4* src = (const float4*)(v + (size_t)g*8192);
    int tid = threadIdx.x;
    float sum = 0.f;
    #pragma unroll
    for (int it = 0; it < 8; it++) {
        float4 x = src[tid + it*256];
        sum += x.x + x.y + x.z + x.w;
    }
    #pragma unroll
    for (int off = 32; off; off >>= 1) sum += __shfl_down(sum, off, 64);
    __shared__ float partial[4];
    if ((tid & 63) == 0) partial[tid >> 6] = sum;
    __syncthreads();
    if (tid == 0) vm[g] = (partial[0]+partial[1]+partial[2]+partial[3]) * (1.0f/8192.0f);
}

// ---------------------------------------------------------------------------
// K4: fused conv1(1x3, 8->3) + relu + depthwise conv2(3x3) + relu  -> A[b][kk][i][j]
// grid = BB * (P/16); each block: one b, 16-row strip
// ---------------------------------------------------------------------------
__global__ __launch_bounds__(256) void k_conv(
    const float* __restrict__ attn, const float* __restrict__ W1,
    const float* __restrict__ b1, const float* __restrict__ W2,
    const float* __restrict__ b2, float* __restrict__ A)
{
    int blk = blockIdx.x;
    int strip = blk & 7, b = blk >> 3;
    int i0 = strip * 16;
    __shared__ float a1s[3][18][128];
    __shared__ float w1s[72], w2s[27], b1s[3], b2s[3];
    int tid = threadIdx.x;
    if (tid < 72) w1s[tid] = W1[tid];
    else if (tid < 99) w2s[tid-72] = W2[tid-72];
    else if (tid < 102) b1s[tid-99] = b1[tid-99];
    else if (tid < 105) b2s[tid-102] = b2[tid-102];
    __syncthreads();
    const float* abase = attn + (size_t)b*NH*HW;
    // step 1: a1 rows i0-1 .. i0+16  (3 kk * 18 rows * 128 j = 6912 = 27*256)
    for (int it = 0; it < 27; it++) {
        int f = tid + it*256;
        int j = f & 127;
        int r = (f >> 7) % 18;
        int kk = f / 2304;
        int i = i0 - 1 + r;
        float vres = 0.f;
        if (i >= 0 && i < P) {
            float s = b1s[kk];
            #pragma unroll
            for (int n = 0; n < 8; n++) {
                const float* ar = abase + (size_t)n*HW + (size_t)i*W;
                float x0 = (j > 0)   ? ar[j-1] : 0.f;
                float x1 = ar[j];
                float x2 = (j < 127) ? ar[j+1] : 0.f;
                s += x0*w1s[kk*24+n*3+0] + x1*w1s[kk*24+n*3+1] + x2*w1s[kk*24+n*3+2];
            }
            vres = fmaxf(s, 0.f);
        }
        a1s[kk][r][j] = vres;
    }
    __syncthreads();
    // step 2: depthwise 3x3 on a1s -> A rows i0..i0+15 (3*16*128 = 6144 = 24*256)
    for (int it = 0; it < 24; it++) {
        int f = tid + it*256;
        int j = f & 127;
        int lr = (f >> 7) & 15;
        int kk = f >> 11;
        float s = b2s[kk];
        #pragma unroll
        for (int u = 0; u < 3; u++) {
            #pragma unroll
            for (int t = 0; t < 3; t++) {
                int jj = j + t - 1;
                float x = (jj >= 0 && jj < 128) ? a1s[kk][lr+u][jj] : 0.f;
                s += x * w2s[kk*9+u*3+t];
            }
        }
        A[(((size_t)b*3 + kk)*P + (i0+lr))*P + j] = fmaxf(s, 0.f);
    }
}

// ---------------------------------------------------------------------------
// K5: attn_new[bw][n][i][j] = sum_m attn[bw][n][i][j+m-1] * A[bw][m][i][j] * V[bw][n][m]
//     V[bw][n][m] = vm[bw][n]*Wl[m] + bl[m]
// grid = BB*P blocks (bw,i); 256 threads = 8 n-groups x 32
// ---------------------------------------------------------------------------
__global__ __launch_bounds__(256) void k_attn_new(
    const float* __restrict__ attn, const float* __restrict__ A,
    const float* __restrict__ vm, const float* __restrict__ Wl,
    const float* __restrict__ bl, float* __restrict__ anew)
{
    int blk = blockIdx.x;
    int i = blk & 127, bw = blk >> 7;
    __shared__ float As[3][128];
    __shared__ float rows[8][130];
    __shared__ float Vs[8][3];
    int tid = threadIdx.x;
    for (int f = tid; f < 384; f += 256) {
        int m = f >> 7, j = f & 127;
        As[m][j] = A[(((size_t)bw*3 + m)*P + i)*P + j];
    }
    if (tid < 24) {
        int n = tid / 3, m = tid % 3;
        Vs[n][m] = vm[bw*8 + n] * Wl[m] + bl[m];
    }
    const float* ab = attn + (size_t)bw*NH*HW + (size_t)i*W;
    #pragma unroll
    for (int f0 = 0; f0 < 1024; f0 += 256) {
        int f = tid + f0;
        int n = f >> 7, j = f & 127;
        rows[n][j+1] = ab[(size_t)n*HW + j];
    }
    if (tid < 8) { rows[tid][0] = 0.f; rows[tid][129] = 0.f; }
    __syncthreads();
    int n = tid >> 5, jj = tid & 31;
    float v0 = Vs[n][0], v1 = Vs[n][1], v2 = Vs[n][2];
    float* dst = anew + ((size_t)bw*NH + n)*HW + (size_t)i*W;
    #pragma unroll
    for (int q = 0; q < 4; q++) {
        int j = jj + q*32;
        float r = rows[n][j]*As[0][j]*v0 + rows[n][j+1]*As[1][j]*v1 + rows[n][j+2]*As[2][j]*v2;
        dst[j] = r;
    }
}

// ---------------------------------------------------------------------------
// K6: out_pre[bw][n][i][dd] = sum_j anew[bw][n][i][j] * v[bw][n][j][dd]
// grid = BB*NH blocks; per-block 128x64 output, K=128
// ---------------------------------------------------------------------------
__global__ __launch_bounds__(256) void k_gemm_av(
    const float* __restrict__ anew, const float* __restrict__ v,
    float* __restrict__ op)
{
    int g = blockIdx.x;
    const float* Abase = anew + (size_t)g*HW;      // [i][j]
    const float* Bbase = v + (size_t)g*8192;       // [j][dd]
    float* obase = op + (size_t)g*8192;            // [i][dd]
    __shared__ float sAT[16][132];  // [jc][i]
    __shared__ float sB[16][68];    // [jc][dd]
    int tid = threadIdx.x;
    int tx = tid & 15, ty = tid >> 4;
    float acc[8][4] = {};
    for (int j0 = 0; j0 < 128; j0 += 16) {
        #pragma unroll
        for (int it = 0; it < 8; it++) {
            int f = tid + it*256;
            int i = f >> 4, jc = f & 15;
            sAT[jc][i] = Abase[(size_t)i*128 + j0 + jc];
        }
        #pragma unroll
        for (int it = 0; it < 4; it++) {
            int f = tid + it*256;
            int jc = f >> 6, dd = f & 63;
            sB[jc][dd] = Bbase[(size_t)(j0+jc)*64 + dd];
        }
        __syncthreads();
        #pragma unroll
        for (int jc = 0; jc < 16; jc++) {
            float a[8], br[4];
            #pragma unroll
            for (int m = 0; m < 8; m++) a[m] = sAT[jc][ty*8+m];
            #pragma unroll
            for (int n2 = 0; n2 < 4; n2++) br[n2] = sB[jc][tx*4+n2];
            #pragma unroll
            for (int m = 0; m < 8; m++)
                #pragma unroll
                for (int n2 = 0; n2 < 4; n2++) acc[m][n2] += a[m]*br[n2];
        }
        __syncthreads();
    }
    #pragma unroll
    for (int m = 0; m < 8; m++) {
        float* dst = obase + (size_t)(ty*8+m)*64 + tx*4;
        dst[0]=acc[m][0]; dst[1]=acc[m][1]; dst[2]=acc[m][2]; dst[3]=acc[m][3];
    }
}

// ---------------------------------------------------------------------------
// K7: final[b][o][i][w] = bo[o] + sum_c Wo[o][c] * out_pre[(b*W+w)][n][i][dd]
//     (c = n*64+dd);  grid.x = BATCH*P (b,i), grid.y = C/128
// ---------------------------------------------------------------------------
__global__ __launch_bounds__(256) void k_gemm_out(
    const float* __restrict__ op, const float* __restrict__ Wo,
    const float* __restrict__ bo, float* __restrict__ out)
{
    int row = blockIdx.x;
    int b = row >> 7, i = row & 127;
    int o0 = blockIdx.y * 128;
    __shared__ float sW[32][132];   // [cc][m]
    __shared__ float sX[32][132];   // [cc][w]
    int tid = threadIdx.x;
    int tx = tid & 15, ty = tid >> 4;
    float acc[8][8] = {};
    const float* opbase = op + (size_t)(b*W)*65536 + (size_t)i*64;
    for (int chunk = 0; chunk < 16; chunk++) {   // c0 = chunk*32
        int c0 = chunk*32;
        int n = c0 >> 6, ddb = c0 & 63;
        #pragma unroll
        for (int it = 0; it < 16; it++) {
            int f = tid + it*256;
            int m = f >> 5, cc = f & 31;
            sW[cc][m] = Wo[(size_t)(o0+m)*C + c0 + cc];
        }
        #pragma unroll
        for (int it = 0; it < 16; it++) {
            int f = tid + it*256;
            int w = f >> 5, cc = f & 31;
            sX[cc][w] = opbase[(size_t)w*65536 + (size_t)n*8192 + ddb + cc];
        }
        __syncthreads();
        #pragma unroll
        for (int cc = 0; cc < 32; cc++) {
            float a[8], br[8];
            #pragma unroll
            for (int m = 0; m < 8; m++) a[m] = sW[cc][ty*8+m];
            #pragma unroll
            for (int nn = 0; nn < 8; nn++) br[nn] = sX[cc][tx*8+nn];
            #pragma unroll
            for (int m = 0; m < 8; m++)
                #pragma unroll
                for (int nn = 0; nn < 8; nn++) acc[m][nn] += a[m]*br[nn];
        }
        __syncthreads();
    }
    #pragma unroll
    for (int m = 0; m < 8; m++) {
        int o = o0 + ty*8 + m;
        float bias = bo[o];
        float* dst = out + (size_t)b*CHW + (size_t)o*HW + (size_t)i*W + tx*8;
        #pragma unroll
        for (int n = 0; n < 8; n++) dst[n] = acc[m][n] + bias;
    }
}

// ---------------------------------------------------------------------------
extern "C" void kernel_launch(void* const* d_in, const int* in_sizes, int n_in,
                              void* d_out, int out_size, void* d_ws, size_t ws_size,
                              hipStream_t stream)
{
    const float* X    = (const float*)d_in[0];   // "output" input [4,512,128,128]
    const float* attn = (const float*)d_in[1];   // [512,8,128,128]
    const float* Wv   = (const float*)d_in[2];
    const float* bv   = (const float*)d_in[3];
    const float* W1   = (const float*)d_in[4];
    const float* b1   = (const float*)d_in[5];
    const float* W2   = (const float*)d_in[6];
    const float* b2   = (const float*)d_in[7];
    const float* Wl   = (const float*)d_in[8];
    const float* bl   = (const float*)d_in[9];
    const float* Wo   = (const float*)d_in[10];
    const float* bo   = (const float*)d_in[11];

    float* out  = (float*)d_out;                  // [0, 33554432): final out (written last by K7)
    float* anew = (float*)d_out + OUT0_SIZE;      // attn_new (second output)

    // A[512][3][128][128] = 25165824 floats lives in the *out* region of d_out:
    // it is fully consumed by K5 before K7 overwrites every element of out.
    float* A = out;

    float* ws = (float*)d_ws;
    float* value   = ws;                           // 33554432 floats (reused by out_pre)
    float* v       = ws + 33554432;                // 33554432 floats
    float* vm      = ws + 67108864;                // 4096 floats
    float* out_pre = value;                        // reuse (value dead after transpose)

    // 1. value conv (1x1 GEMM)
    k_gemm_value<<<dim3(BATCH*H, C/128), 256, 0, stream>>>(X, Wv, bv, value);
    // 2. transpose to v
    k_transpose_v<<<BATCH*NH*P, 256, 0, stream>>>(value, v);
    // 3. vm mean
    k_vm<<<BB*NH, 256, 0, stream>>>(v, vm);
    // 4. fused adaptive-kernel convs -> A
    k_conv<<<BB*(P/16), 256, 0, stream>>>(attn, W1, b1, W2, b2, A);
    // 5. involution -> attn_new (second output)
    k_attn_new<<<BB*P, 256, 0, stream>>>(attn, A, vm, Wl, bl, anew);
    // 6. attn_new @ v -> out_pre
    k_gemm_av<<<BB*NH, 256, 0, stream>>>(anew, v, out_pre);
    // 7. fold + out conv (1x1 GEMM) -> out  (overwrites the A scratch region)
    k_gemm_out<<<dim3(BATCH*P, C/128), 256, 0, stream>>>(out_pre, Wo, bo, out);
}

// Round 5
// 1589.283 us; speedup vs baseline: 1.2379x; 1.2379x over previous
//
#include <hip/hip_runtime.h>
#include <hip/hip_bf16.h>

typedef __attribute__((ext_vector_type(8))) short bf16x8;
typedef __attribute__((ext_vector_type(4))) float f32x4;
typedef __attribute__((ext_vector_type(4))) unsigned short u16x4;

#define BATCH 4
#define C 512
#define H 128
#define W 128
#define HW (H*W)            // 16384
#define CHW (C*HW)          // 8388608
#define NH 8
#define D 64
#define P 128
#define BB (BATCH*W)        // 512
#define OUT0_SIZE ((size_t)BATCH*C*H*W)   // 33554432

// round-to-nearest-even f32 -> bf16 bits
__device__ __forceinline__ unsigned short f2bf(float x) {
    unsigned u = __float_as_uint(x);
    unsigned r = u + 0x7fffu + ((u >> 16) & 1u);
    return (unsigned short)(r >> 16);
}
__device__ __forceinline__ float bf2f(unsigned short b) {
    return __uint_as_float(((unsigned)b) << 16);
}

// ---------------------------------------------------------------------------
// T0: convert a f32 matrix to bf16 hi/lo planes
// ---------------------------------------------------------------------------
__global__ __launch_bounds__(256) void k_cvt_w(
    const float* __restrict__ src, unsigned short* __restrict__ hi,
    unsigned short* __restrict__ lo, int n)
{
    int idx = blockIdx.x * 256 + threadIdx.x;
    if (idx < n) {
        float x = src[idx];
        unsigned short h = f2bf(x);
        unsigned short l = f2bf(x - bf2f(h));
        hi[idx] = h; lo[idx] = l;
    }
}

// ---------------------------------------------------------------------------
// T1: Xt[(b*128+i)*128+w][c] (bf16 hi/lo) = X[b][c][i][w]   (c contiguous)
// grid = 4 b * 128 i * 8 cblk = 4096
// ---------------------------------------------------------------------------
__global__ __launch_bounds__(256) void k_xt(
    const float* __restrict__ X, unsigned short* __restrict__ Xh,
    unsigned short* __restrict__ Xl)
{
    int blk = blockIdx.x;
    int cblk = blk & 7, i = (blk >> 3) & 127, b = blk >> 10;
    int c0 = cblk * 64;
    __shared__ float s[64][129];
    int tid = threadIdx.x;
    const float* src = X + (size_t)b*CHW + (size_t)c0*HW + (size_t)i*W;
    #pragma unroll
    for (int it = 0; it < 32; it++) {
        int f = tid + it*256;
        int w = f & 127, cc = f >> 7;
        s[cc][w] = src[(size_t)cc*HW + w];
    }
    __syncthreads();
    size_t dbase = ((size_t)(b*128 + i)*128)*512 + c0;
    #pragma unroll
    for (int it = 0; it < 32; it++) {
        int f = tid + it*256;
        int cc = f & 63, w = f >> 6;
        float x = s[cc][w];
        unsigned short h = f2bf(x);
        unsigned short l = f2bf(x - bf2f(h));
        size_t idx = dbase + (size_t)w*512 + cc;
        Xh[idx] = h; Xl[idx] = l;
    }
}

// ---------------------------------------------------------------------------
// K1'': split-bf16 MFMA value conv, writes v[bw][n][i][dd] directly.
// D[m=w][n=o]: A slots = w (Xt, c contig), B slots = o (Wv planes, c contig).
// grid = (512 bi, 4 otile), 256 thr = 4 waves x 32 w.
// ---------------------------------------------------------------------------
__global__ __launch_bounds__(256) void k_gemm_value_mfma(
    const unsigned short* __restrict__ Xh, const unsigned short* __restrict__ Xl,
    const unsigned short* __restrict__ Wh, const unsigned short* __restrict__ Wl,
    const float* __restrict__ bv, float* __restrict__ v)
{
    const int bi = blockIdx.x;
    const int b = bi >> 7, i = bi & 127;
    const int o0 = blockIdx.y * 128;
    const int tid = threadIdx.x;
    const int wave = tid >> 6, lane = tid & 63;
    const int sl = lane & 15, g = lane >> 4;
    const int w0 = wave * 32;

    const unsigned short* a0h = Xh + ((size_t)bi*128 + w0 + sl)*512 + g*8;
    const unsigned short* a0l = Xl + ((size_t)bi*128 + w0 + sl)*512 + g*8;
    const unsigned short* bh  = Wh + (size_t)(o0 + sl)*512 + g*8;
    const unsigned short* bl  = Wl + (size_t)(o0 + sl)*512 + g*8;

    f32x4 acc[2][8];
    #pragma unroll
    for (int ms = 0; ms < 2; ms++)
        #pragma unroll
        for (int ns = 0; ns < 8; ns++) acc[ms][ns] = (f32x4){0.f,0.f,0.f,0.f};

    for (int c0 = 0; c0 < 512; c0 += 32) {
        bf16x8 Ah0 = *(const bf16x8*)(a0h + c0);
        bf16x8 Al0 = *(const bf16x8*)(a0l + c0);
        bf16x8 Ah1 = *(const bf16x8*)(a0h + 16*512 + c0);
        bf16x8 Al1 = *(const bf16x8*)(a0l + 16*512 + c0);
        #pragma unroll
        for (int ns = 0; ns < 8; ns++) {
            bf16x8 Bh = *(const bf16x8*)(bh + (size_t)ns*16*512 + c0);
            bf16x8 Bl = *(const bf16x8*)(bl + (size_t)ns*16*512 + c0);
            acc[0][ns] = __builtin_amdgcn_mfma_f32_16x16x32_bf16(Ah0, Bh, acc[0][ns], 0,0,0);
            acc[0][ns] = __builtin_amdgcn_mfma_f32_16x16x32_bf16(Al0, Bh, acc[0][ns], 0,0,0);
            acc[0][ns] = __builtin_amdgcn_mfma_f32_16x16x32_bf16(Ah0, Bl, acc[0][ns], 0,0,0);
            acc[1][ns] = __builtin_amdgcn_mfma_f32_16x16x32_bf16(Ah1, Bh, acc[1][ns], 0,0,0);
            acc[1][ns] = __builtin_amdgcn_mfma_f32_16x16x32_bf16(Al1, Bh, acc[1][ns], 0,0,0);
            acc[1][ns] = __builtin_amdgcn_mfma_f32_16x16x32_bf16(Ah1, Bl, acc[1][ns], 0,0,0);
        }
    }
    // epilogue: v[(b*128+w)*65536 + (o>>6)*8192 + i*64 + (o&63)] = acc + bv[o]
    #pragma unroll
    for (int ns = 0; ns < 8; ns++) {
        int o = o0 + ns*16 + sl;
        float bias = bv[o];
        size_t vb = (size_t)(b*128)*65536 + (size_t)(o >> 6)*8192 + (size_t)i*64 + (o & 63);
        #pragma unroll
        for (int ms = 0; ms < 2; ms++) {
            #pragma unroll
            for (int r = 0; r < 4; r++) {
                int w = w0 + ms*16 + g*4 + r;
                v[vb + (size_t)w*65536] = acc[ms][ns][r] + bias;
            }
        }
    }
}

// ---------------------------------------------------------------------------
// K3: vm[g] = mean(v[g*8192 .. +8192))
// ---------------------------------------------------------------------------
__global__ __launch_bounds__(256) void k_vm(
    const float* __restrict__ v, float* __restrict__ vm)
{
    int g = blockIdx.x;
    const float4* src = (const float4*)(v + (size_t)g*8192);
    int tid = threadIdx.x;
    float sum = 0.f;
    #pragma unroll
    for (int it = 0; it < 8; it++) {
        float4 x = src[tid + it*256];
        sum += x.x + x.y + x.z + x.w;
    }
    #pragma unroll
    for (int off = 32; off; off >>= 1) sum += __shfl_down(sum, off, 64);
    __shared__ float partial[4];
    if ((tid & 63) == 0) partial[tid >> 6] = sum;
    __syncthreads();
    if (tid == 0) vm[g] = (partial[0]+partial[1]+partial[2]+partial[3]) * (1.0f/8192.0f);
}

// ---------------------------------------------------------------------------
// K4: fused conv1 + relu + depthwise conv2 + relu -> A[b][kk][i][j]
// ---------------------------------------------------------------------------
__global__ __launch_bounds__(256) void k_conv(
    const float* __restrict__ attn, const float* __restrict__ W1,
    const float* __restrict__ b1, const float* __restrict__ W2,
    const float* __restrict__ b2, float* __restrict__ A)
{
    int blk = blockIdx.x;
    int strip = blk & 7, b = blk >> 3;
    int i0 = strip * 16;
    __shared__ float a1s[3][18][128];
    __shared__ float w1s[72], w2s[27], b1s[3], b2s[3];
    int tid = threadIdx.x;
    if (tid < 72) w1s[tid] = W1[tid];
    else if (tid < 99) w2s[tid-72] = W2[tid-72];
    else if (tid < 102) b1s[tid-99] = b1[tid-99];
    else if (tid < 105) b2s[tid-102] = b2[tid-102];
    __syncthreads();
    const float* abase = attn + (size_t)b*NH*HW;
    for (int it = 0; it < 27; it++) {
        int f = tid + it*256;
        int j = f & 127;
        int r = (f >> 7) % 18;
        int kk = f / 2304;
        int i = i0 - 1 + r;
        float vres = 0.f;
        if (i >= 0 && i < P) {
            float s = b1s[kk];
            #pragma unroll
            for (int n = 0; n < 8; n++) {
                const float* ar = abase + (size_t)n*HW + (size_t)i*W;
                float x0 = (j > 0)   ? ar[j-1] : 0.f;
                float x1 = ar[j];
                float x2 = (j < 127) ? ar[j+1] : 0.f;
                s += x0*w1s[kk*24+n*3+0] + x1*w1s[kk*24+n*3+1] + x2*w1s[kk*24+n*3+2];
            }
            vres = fmaxf(s, 0.f);
        }
        a1s[kk][r][j] = vres;
    }
    __syncthreads();
    for (int it = 0; it < 24; it++) {
        int f = tid + it*256;
        int j = f & 127;
        int lr = (f >> 7) & 15;
        int kk = f >> 11;
        float s = b2s[kk];
        #pragma unroll
        for (int u = 0; u < 3; u++) {
            #pragma unroll
            for (int t = 0; t < 3; t++) {
                int jj = j + t - 1;
                float x = (jj >= 0 && jj < 128) ? a1s[kk][lr+u][jj] : 0.f;
                s += x * w2s[kk*9+u*3+t];
            }
        }
        A[(((size_t)b*3 + kk)*P + (i0+lr))*P + j] = fmaxf(s, 0.f);
    }
}

// ---------------------------------------------------------------------------
// K5: involution -> attn_new
// ---------------------------------------------------------------------------
__global__ __launch_bounds__(256) void k_attn_new(
    const float* __restrict__ attn, const float* __restrict__ A,
    const float* __restrict__ vm, const float* __restrict__ Wl,
    const float* __restrict__ bl, float* __restrict__ anew)
{
    int blk = blockIdx.x;
    int i = blk & 127, bw = blk >> 7;
    __shared__ float As[3][128];
    __shared__ float rows[8][130];
    __shared__ float Vs[8][3];
    int tid = threadIdx.x;
    for (int f = tid; f < 384; f += 256) {
        int m = f >> 7, j = f & 127;
        As[m][j] = A[(((size_t)bw*3 + m)*P + i)*P + j];
    }
    if (tid < 24) {
        int n = tid / 3, m = tid % 3;
        Vs[n][m] = vm[bw*8 + n] * Wl[m] + bl[m];
    }
    const float* ab = attn + (size_t)bw*NH*HW + (size_t)i*W;
    #pragma unroll
    for (int f0 = 0; f0 < 1024; f0 += 256) {
        int f = tid + f0;
        int n = f >> 7, j = f & 127;
        rows[n][j+1] = ab[(size_t)n*HW + j];
    }
    if (tid < 8) { rows[tid][0] = 0.f; rows[tid][129] = 0.f; }
    __syncthreads();
    int n = tid >> 5, jj = tid & 31;
    float v0 = Vs[n][0], v1 = Vs[n][1], v2 = Vs[n][2];
    float* dst = anew + ((size_t)bw*NH + n)*HW + (size_t)i*W;
    #pragma unroll
    for (int q = 0; q < 4; q++) {
        int j = jj + q*32;
        float r = rows[n][j]*As[0][j]*v0 + rows[n][j+1]*As[1][j]*v1 + rows[n][j+2]*As[2][j]*v2;
        dst[j] = r;
    }
}

// ---------------------------------------------------------------------------
// K6: out_pre = anew @ v  (f32 VALU), epilogue emits bf16 hi/lo planes
// ---------------------------------------------------------------------------
__global__ __launch_bounds__(256) void k_gemm_av(
    const float* __restrict__ anew, const float* __restrict__ v,
    unsigned short* __restrict__ oph, unsigned short* __restrict__ opl)
{
    int g = blockIdx.x;
    const float* Abase = anew + (size_t)g*HW;
    const float* Bbase = v + (size_t)g*8192;
    __shared__ float sAT[16][132];
    __shared__ float sB[16][68];
    int tid = threadIdx.x;
    int tx = tid & 15, ty = tid >> 4;
    float acc[8][4] = {};
    for (int j0 = 0; j0 < 128; j0 += 16) {
        #pragma unroll
        for (int it = 0; it < 8; it++) {
            int f = tid + it*256;
            int i = f >> 4, jc = f & 15;
            sAT[jc][i] = Abase[(size_t)i*128 + j0 + jc];
        }
        #pragma unroll
        for (int it = 0; it < 4; it++) {
            int f = tid + it*256;
            int jc = f >> 6, dd = f & 63;
            sB[jc][dd] = Bbase[(size_t)(j0+jc)*64 + dd];
        }
        __syncthreads();
        #pragma unroll
        for (int jc = 0; jc < 16; jc++) {
            float a[8], br[4];
            #pragma unroll
            for (int m = 0; m < 8; m++) a[m] = sAT[jc][ty*8+m];
            #pragma unroll
            for (int n2 = 0; n2 < 4; n2++) br[n2] = sB[jc][tx*4+n2];
            #pragma unroll
            for (int m = 0; m < 8; m++)
                #pragma unroll
                for (int n2 = 0; n2 < 4; n2++) acc[m][n2] += a[m]*br[n2];
        }
        __syncthreads();
    }
    #pragma unroll
    for (int m = 0; m < 8; m++) {
        size_t base = (size_t)g*8192 + (size_t)(ty*8+m)*64 + tx*4;
        u16x4 hv, lv;
        #pragma unroll
        for (int n2 = 0; n2 < 4; n2++) {
            float x = acc[m][n2];
            unsigned short h = f2bf(x);
            unsigned short l = f2bf(x - bf2f(h));
            hv[n2] = h; lv[n2] = l;
        }
        *(u16x4*)(oph + base) = hv;
        *(u16x4*)(opl + base) = lv;
    }
}

// ---------------------------------------------------------------------------
// K7'': split-bf16 MFMA out conv. D[m=o][n=w]: A = Wo (f32, split on the fly,
// c contig), B = op hi/lo planes (c contig in 64-runs). Writes out[b][o][i][w].
// grid = (512 bi, 4 otile), 256 thr = 4 waves x 32 o.
// ---------------------------------------------------------------------------
__global__ __launch_bounds__(256) void k_gemm_out_mfma(
    const unsigned short* __restrict__ Ph, const unsigned short* __restrict__ Pl,
    const float* __restrict__ Wo, const float* __restrict__ bo,
    float* __restrict__ out)
{
    const int bi = blockIdx.x;
    const int b = bi >> 7, i = bi & 127;
    const int tid = threadIdx.x;
    const int wave = tid >> 6, lane = tid & 63;
    const int sl = lane & 15, g = lane >> 4;
    const int ow = blockIdx.y * 128 + wave * 32;

    const float* wo0 = Wo + (size_t)(ow + sl)*512 + g*8;
    const size_t pb = (size_t)(b*128 + sl)*65536 + (size_t)i*64;

    f32x4 acc[2][8];
    #pragma unroll
    for (int ms = 0; ms < 2; ms++)
        #pragma unroll
        for (int ns = 0; ns < 8; ns++) acc[ms][ns] = (f32x4){0.f,0.f,0.f,0.f};

    for (int c0 = 0; c0 < 512; c0 += 32) {
        int cA = c0 + g*8;
        bf16x8 Ah0, Al0, Ah1, Al1;
        #pragma unroll
        for (int e = 0; e < 8; e++) {
            float x = wo0[c0 + e];
            unsigned short h = f2bf(x);
            Ah0[e] = (short)h; Al0[e] = (short)f2bf(x - bf2f(h));
        }
        #pragma unroll
        for (int e = 0; e < 8; e++) {
            float x = wo0[16*512 + c0 + e];
            unsigned short h = f2bf(x);
            Ah1[e] = (short)h; Al1[e] = (short)f2bf(x - bf2f(h));
        }
        size_t coff = (size_t)(cA >> 6)*8192 + (cA & 63);
        #pragma unroll
        for (int ns = 0; ns < 8; ns++) {
            const unsigned short* bp = Ph + pb + (size_t)ns*16*65536 + coff;
            const unsigned short* bq = Pl + pb + (size_t)ns*16*65536 + coff;
            bf16x8 Bh = *(const bf16x8*)bp;
            bf16x8 Bl = *(const bf16x8*)bq;
            acc[0][ns] = __builtin_amdgcn_mfma_f32_16x16x32_bf16(Ah0, Bh, acc[0][ns], 0,0,0);
            acc[0][ns] = __builtin_amdgcn_mfma_f32_16x16x32_bf16(Al0, Bh, acc[0][ns], 0,0,0);
            acc[0][ns] = __builtin_amdgcn_mfma_f32_16x16x32_bf16(Ah0, Bl, acc[0][ns], 0,0,0);
            acc[1][ns] = __builtin_amdgcn_mfma_f32_16x16x32_bf16(Ah1, Bh, acc[1][ns], 0,0,0);
            acc[1][ns] = __builtin_amdgcn_mfma_f32_16x16x32_bf16(Al1, Bh, acc[1][ns], 0,0,0);
            acc[1][ns] = __builtin_amdgcn_mfma_f32_16x16x32_bf16(Ah1, Bl, acc[1][ns], 0,0,0);
        }
    }
    // epilogue: out[b][o][i][w] = acc + bo[o]
    #pragma unroll
    for (int ms = 0; ms < 2; ms++) {
        #pragma unroll
        for (int r = 0; r < 4; r++) {
            int o = ow + ms*16 + g*4 + r;
            float bias = bo[o];
            float* dst = out + (size_t)b*CHW + (size_t)o*HW + (size_t)i*W;
            #pragma unroll
            for (int ns = 0; ns < 8; ns++) {
                dst[ns*16 + sl] = acc[ms][ns][r] + bias;
            }
        }
    }
}

// ---------------------------------------------------------------------------
extern "C" void kernel_launch(void* const* d_in, const int* in_sizes, int n_in,
                              void* d_out, int out_size, void* d_ws, size_t ws_size,
                              hipStream_t stream)
{
    const float* X    = (const float*)d_in[0];
    const float* attn = (const float*)d_in[1];
    const float* Wv   = (const float*)d_in[2];
    const float* bv   = (const float*)d_in[3];
    const float* W1   = (const float*)d_in[4];
    const float* b1   = (const float*)d_in[5];
    const float* W2   = (const float*)d_in[6];
    const float* b2   = (const float*)d_in[7];
    const float* Wl   = (const float*)d_in[8];
    const float* bl   = (const float*)d_in[9];
    const float* Wo   = (const float*)d_in[10];
    const float* bo   = (const float*)d_in[11];

    float* out  = (float*)d_out;                   // final out (written last by K7)
    float* anew = (float*)d_out + OUT0_SIZE;       // attn_new (second output)

    // Scratch packed in the dead tail of the out region:
    //   A: [0, 25165824)  (K4 -> K5, dead before K7 overwrites)
    //   wv planes: [25165824, 25427968)  (T0 -> K1'', dead before K7)
    //   vm: [25427968, 25432064)         (K3 -> K5, dead before K7)
    float* A = out;
    unsigned short* wvh = (unsigned short*)(out + 25165824);
    unsigned short* wvl = (unsigned short*)(out + 25296896);
    float* vm = out + 25427968;

    float* ws = (float*)d_ws;
    float* v = ws;                                           // 128 MB f32
    unsigned short* xth = (unsigned short*)(ws + 33554432);  // 64 MB bf16
    unsigned short* xtl = (unsigned short*)(ws + 50331648);  // 64 MB bf16
    unsigned short* oph = xth;  // reuse: Xt dead after K1''
    unsigned short* opl = xtl;

    // T0: Wv -> bf16 hi/lo planes
    k_cvt_w<<<1024, 256, 0, stream>>>(Wv, wvh, wvl, 262144);
    // T1: X -> Xt[s][c] bf16 hi/lo (transposed, c contiguous)
    k_xt<<<4096, 256, 0, stream>>>(X, xth, xtl);
    // K1'': value conv (split MFMA), writes v directly (K2 eliminated)
    k_gemm_value_mfma<<<dim3(512, 4), 256, 0, stream>>>(xth, xtl, wvh, wvl, bv, v);
    // K3: vm mean
    k_vm<<<BB*NH, 256, 0, stream>>>(v, vm);
    // K4: adaptive-kernel convs -> A
    k_conv<<<BB*(P/16), 256, 0, stream>>>(attn, W1, b1, W2, b2, A);
    // K5: involution -> attn_new
    k_attn_new<<<BB*P, 256, 0, stream>>>(attn, A, vm, Wl, bl, anew);
    // K6: attn_new @ v -> op bf16 hi/lo planes (into old Xt region)
    k_gemm_av<<<BB*NH, 256, 0, stream>>>(anew, v, oph, opl);
    // K7'': out conv (split MFMA) -> out
    k_gemm_out_mfma<<<dim3(512, 4), 256, 0, stream>>>(oph, opl, Wo, bo, out);
}